// Round 2
// baseline (2185.463 us; speedup 1.0000x reference)
//
#include <hip/hip_runtime.h>
#include <math.h>

#define F0 1433
#define F1 32
#define F2 7

// ---------------- degree / dinv ----------------
__global__ void k_init_deg(float* __restrict__ deg, int N) {
    int i = blockIdx.x * 256 + threadIdx.x;
    if (i < N) deg[i] = 1.0f;   // self-loop contributes 1
}

__global__ void k_count_deg(const int* __restrict__ dst, float* __restrict__ deg, int E) {
    int e = blockIdx.x * 256 + threadIdx.x;
    if (e < E) atomicAdd(&deg[dst[e]], 1.0f);
}

__global__ void k_dinv(float* __restrict__ deg, int N) {
    int i = blockIdx.x * 256 + threadIdx.x;
    if (i < N) deg[i] = rsqrtf(deg[i]);   // deg >= 1 always (self-loops)
}

// ---------------- GEMM1: h1[N,32] = x[N,1433] @ W1[1433,32] ----------------
// Streaming register GEMM: no LDS, no barriers. Lane owns (row, 4-col group).
// 8 lanes share each x float4 (coalescer broadcast); W is L2-resident (183 KB).
// Epilogue also writes agg1 = h1 * dinv^2 (self-loop init for layer-1 agg).
__global__ __launch_bounds__(256) void k_gemm1(const float* __restrict__ x,
                                               const float* __restrict__ W,
                                               const float* __restrict__ dinv,
                                               float* __restrict__ h,
                                               float* __restrict__ agg, int N) {
    const int tid = threadIdx.x;
    const int r   = blockIdx.x * 32 + (tid >> 3);   // 32 rows per block
    const int cg  = tid & 7;                        // 8 col-groups of 4
    if (r >= N) return;

    const float* __restrict__ xr = x + (long)r * F0;
    const float* __restrict__ wc = W + cg * 4;

    float ax = 0.f, ay = 0.f, az = 0.f, aw = 0.f;

    // 1432 = 8 * 179 ; last k (=1432) handled as scalar tail
    for (int k = 0; k < 1432; k += 8) {
        float4 xa = *(const float4*)(xr + k);
        float4 xb = *(const float4*)(xr + k + 4);
        #pragma unroll
        for (int u = 0; u < 4; ++u) {
            float4 w = *(const float4*)(wc + (long)(k + u) * F1);
            float a = (u == 0) ? xa.x : (u == 1) ? xa.y : (u == 2) ? xa.z : xa.w;
            ax += a * w.x; ay += a * w.y; az += a * w.z; aw += a * w.w;
        }
        #pragma unroll
        for (int u = 0; u < 4; ++u) {
            float4 w = *(const float4*)(wc + (long)(k + 4 + u) * F1);
            float a = (u == 0) ? xb.x : (u == 1) ? xb.y : (u == 2) ? xb.z : xb.w;
            ax += a * w.x; ay += a * w.y; az += a * w.z; aw += a * w.w;
        }
    }
    {   // k = 1432 tail
        float a = xr[1432];
        float4 w = *(const float4*)(wc + (long)1432 * F1);
        ax += a * w.x; ay += a * w.y; az += a * w.z; aw += a * w.w;
    }

    float d  = dinv[r];
    float dd = d * d;
    long base = (long)r * F1 + cg * 4;
    *(float4*)&h[base]   = make_float4(ax, ay, az, aw);
    *(float4*)&agg[base] = make_float4(ax * dd, ay * dd, az * dd, aw * dd);
}

// ---------------- layer-1 scatter: one thread per (edge, feature) ----------------
__global__ void k_scatter1(const int* __restrict__ src, const int* __restrict__ dst,
                           const float* __restrict__ dinv, const float* __restrict__ h1,
                           float* __restrict__ agg, int E) {
    int t = blockIdx.x * 256 + threadIdx.x;
    int e = t >> 5;
    if (e >= E) return;
    int f = t & 31;
    int s = src[e], d = dst[e];
    float w = dinv[s] * dinv[d];
    atomicAdd(&agg[d * F1 + f], h1[s * F1 + f] * w);
}

// ---------------- fused: ReLU(agg1+b1) @ W2 -> h2 ; out init = h2*dinv^2 ----------------
__global__ __launch_bounds__(256) void k_layer2(const float* __restrict__ agg1,
                                                const float* __restrict__ b1,
                                                const float* __restrict__ W2,
                                                const float* __restrict__ dinv,
                                                float* __restrict__ h2,
                                                float* __restrict__ out, int N) {
    __shared__ float w2s[F1 * F2];
    __shared__ float b1s[F1];
    int tid = threadIdx.x;
    if (tid < F1 * F2) w2s[tid] = W2[tid];
    if (tid < F1) b1s[tid] = b1[tid];
    __syncthreads();
    int i = blockIdx.x * 256 + tid;
    if (i >= N) return;
    float v[F1];
    #pragma unroll
    for (int u = 0; u < 8; ++u) {
        float4 t = *(const float4*)&agg1[(long)i * F1 + u * 4];
        v[u*4+0] = fmaxf(t.x + b1s[u*4+0], 0.f);
        v[u*4+1] = fmaxf(t.y + b1s[u*4+1], 0.f);
        v[u*4+2] = fmaxf(t.z + b1s[u*4+2], 0.f);
        v[u*4+3] = fmaxf(t.w + b1s[u*4+3], 0.f);
    }
    float o[F2] = {0.f, 0.f, 0.f, 0.f, 0.f, 0.f, 0.f};
    #pragma unroll
    for (int k = 0; k < F1; ++k) {
        float a = v[k];
        #pragma unroll
        for (int c = 0; c < F2; ++c) o[c] += a * w2s[k * F2 + c];
    }
    float di = dinv[i];
    float dd = di * di;
    #pragma unroll
    for (int c = 0; c < F2; ++c) {
        h2[(long)i * F2 + c] = o[c];
        out[(long)i * F2 + c] = o[c] * dd;
    }
}

// ---------------- layer-2 scatter: one thread per (edge, class) ----------------
__global__ void k_scatter2(const int* __restrict__ src, const int* __restrict__ dst,
                           const float* __restrict__ dinv, const float* __restrict__ h2,
                           float* __restrict__ out, int E) {
    int t = blockIdx.x * 256 + threadIdx.x;
    int e = t >> 3;
    int c = t & 7;
    if (e >= E || c >= F2) return;
    int s = src[e], d = dst[e];
    float w = dinv[s] * dinv[d];
    atomicAdd(&out[(long)d * F2 + c], h2[(long)s * F2 + c] * w);
}

// ---------------- +b2 then log_softmax, in place ----------------
__global__ void k_logsoftmax(float* __restrict__ out, const float* __restrict__ b2, int N) {
    int i = blockIdx.x * 256 + threadIdx.x;
    if (i >= N) return;
    float v[F2];
    float m = -1e30f;
    #pragma unroll
    for (int c = 0; c < F2; ++c) {
        v[c] = out[(long)i * F2 + c] + b2[c];
        m = fmaxf(m, v[c]);
    }
    float s = 0.f;
    #pragma unroll
    for (int c = 0; c < F2; ++c) s += expf(v[c] - m);
    float l = logf(s);
    #pragma unroll
    for (int c = 0; c < F2; ++c) out[(long)i * F2 + c] = v[c] - m - l;
}

extern "C" void kernel_launch(void* const* d_in, const int* in_sizes, int n_in,
                              void* d_out, int out_size, void* d_ws, size_t ws_size,
                              hipStream_t stream) {
    const float* x  = (const float*)d_in[0];
    const int*   ei = (const int*)d_in[1];
    const float* W1 = (const float*)d_in[2];
    const float* b1 = (const float*)d_in[3];
    const float* W2 = (const float*)d_in[4];
    const float* b2 = (const float*)d_in[5];
    float* out = (float*)d_out;

    const int N = in_sizes[0] / F0;      // 100000
    const int E = in_sizes[1] / 2;       // 3200000
    const int* src = ei;
    const int* dst = ei + E;

    // workspace layout (floats): dinv[N] | h1[N*32] | agg1[N*32]
    float* ws   = (float*)d_ws;
    size_t o    = 0;
    float* dinv = ws;        o += (size_t)((N + 3) & ~3);
    float* h1   = ws + o;    o += (size_t)N * F1;
    float* agg1 = ws + o;    o += (size_t)N * F1;
    float* h2   = h1;        // h1 is dead after k_scatter1

    const int nb_N = (N + 255) / 256;
    const int nb_E = (E + 255) / 256;

    k_init_deg  <<<nb_N, 256, 0, stream>>>(dinv, N);
    k_count_deg <<<nb_E, 256, 0, stream>>>(dst, dinv, E);
    k_dinv      <<<nb_N, 256, 0, stream>>>(dinv, N);

    k_gemm1     <<<(N + 31) / 32, 256, 0, stream>>>(x, W1, dinv, h1, agg1, N);

    k_scatter1  <<<((size_t)E * 32 + 255) / 256, 256, 0, stream>>>(src, dst, dinv, h1, agg1, E);

    k_layer2    <<<nb_N, 256, 0, stream>>>(agg1, b1, W2, dinv, h2, out, N);

    k_scatter2  <<<((size_t)E * 8 + 255) / 256, 256, 0, stream>>>(src, dst, dinv, h2, out, E);

    k_logsoftmax<<<nb_N, 256, 0, stream>>>(out, b2, N);
}